// Round 1
// baseline (11267.198 us; speedup 1.0000x reference)
//
#include <hip/hip_runtime.h>

#define C 128
#define EPS 1e-5f

// -------- scatter: msgs = x_src[src]*w, atomically accumulated into sums[dst], cnt[dst] += 1 --------
// 32 lanes per edge, one float4 chunk per lane (32*4 = 128 channels).
__global__ __launch_bounds__(256) void scatter_kernel(
    const float* __restrict__ x_src,
    const int* __restrict__ ei,    // [2*E]: [0..E)=src, [E..2E)=dst
    const float* __restrict__ ew,  // [E]
    float* __restrict__ sums,      // [Ndst*C]
    float* __restrict__ cnt,       // [Ndst]
    int E)
{
    int tid = blockIdx.x * blockDim.x + threadIdx.x;
    int e = tid >> 5;
    int g = tid & 31;
    if (e >= E) return;
    int src = ei[e];
    int dst = ei[E + e];
    float w = ew[e];
    const float4* srow = (const float4*)(x_src + (size_t)src * C);
    float4 v = srow[g];
    float* drow = sums + (size_t)dst * C + g * 4;
    atomicAdd(drow + 0, v.x * w);
    atomicAdd(drow + 1, v.y * w);
    atomicAdd(drow + 2, v.z * w);
    atomicAdd(drow + 3, v.w * w);
    if (g == 0) atomicAdd(cnt + dst, 1.0f);
}

// -------- finalize: out = LN(sums/max(cnt,1) + x_dst)*w + b, optional relu --------
// one 64-lane wave per row, 2 channels per lane.
__global__ __launch_bounds__(256) void finalize_kernel(
    const float* __restrict__ sums,
    const float* __restrict__ cnt,
    const float* __restrict__ x_dst,
    const float* __restrict__ lnw,
    const float* __restrict__ lnb,
    float* __restrict__ out,
    int N, int do_relu)
{
    int row = blockIdx.x * (blockDim.x >> 6) + (threadIdx.x >> 6);
    int lane = threadIdx.x & 63;
    if (row >= N) return;
    size_t base = (size_t)row * C;
    float inv = 1.0f / fmaxf(cnt[row], 1.0f);
    float2 s  = ((const float2*)(sums  + base))[lane];
    float2 xd = ((const float2*)(x_dst + base))[lane];
    float2 v;
    v.x = s.x * inv + xd.x;
    v.y = s.y * inv + xd.y;
    float sum = v.x + v.y;
    float sq  = v.x * v.x + v.y * v.y;
    #pragma unroll
    for (int off = 32; off > 0; off >>= 1) {
        sum += __shfl_xor(sum, off, 64);
        sq  += __shfl_xor(sq,  off, 64);
    }
    float mu   = sum * (1.0f / C);
    float var  = sq * (1.0f / C) - mu * mu;
    float rstd = rsqrtf(var + EPS);
    float2 wv = ((const float2*)lnw)[lane];
    float2 bv = ((const float2*)lnb)[lane];
    float2 o;
    o.x = (v.x - mu) * rstd * wv.x + bv.x;
    o.y = (v.y - mu) * rstd * wv.y + bv.y;
    if (do_relu) { o.x = fmaxf(o.x, 0.0f); o.y = fmaxf(o.y, 0.0f); }
    ((float2*)(out + base))[lane] = o;
}

extern "C" void kernel_launch(void* const* d_in, const int* in_sizes, int n_in,
                              void* d_out, int out_size, void* d_ws, size_t ws_size,
                              hipStream_t stream)
{
    const float* x_user = (const float*)d_in[0];
    const float* x_item = (const float*)d_in[1];
    const float* ew_ui  = (const float*)d_in[2];
    const float* ew_iu  = (const float*)d_in[3];
    const float* lnwu0  = (const float*)d_in[4];
    const float* lnbu0  = (const float*)d_in[5];
    const float* lnwu1  = (const float*)d_in[6];
    const float* lnbu1  = (const float*)d_in[7];
    const float* lnwi0  = (const float*)d_in[8];
    const float* lnbi0  = (const float*)d_in[9];
    const float* lnwi1  = (const float*)d_in[10];
    const float* lnbi1  = (const float*)d_in[11];
    const int*   ei_ui  = (const int*)d_in[12];
    const int*   ei_iu  = (const int*)d_in[13];

    const int NU = in_sizes[0] / C;
    const int NI = in_sizes[1] / C;
    const int E  = in_sizes[2];

    float* out   = (float*)d_out;
    float* out_u = out;                    // [NU*C] user activations / final user out
    float* out_i = out + (size_t)NU * C;   // [NI*C] item activations / final item out

    float* sums_u = (float*)d_ws;                    // [NU*C]
    float* sums_i = sums_u + (size_t)NU * C;         // [NI*C]
    float* cnt_u  = sums_i + (size_t)NI * C;         // [NU]
    float* cnt_i  = cnt_u + NU;                      // [NI]
    size_t zero_bytes = ((size_t)NU * C + (size_t)NI * C + NU + NI) * sizeof(float);

    dim3 sblk(256);
    dim3 sgrd((unsigned)(((size_t)E * 32 + 255) / 256));
    dim3 fblk(256);
    dim3 fgrd_u((NU + 3) / 4), fgrd_i((NI + 3) / 4);

    // ---------------- layer 0 ----------------
    hipMemsetAsync(d_ws, 0, zero_bytes, stream);
    scatter_kernel<<<sgrd, sblk, 0, stream>>>(x_item, ei_iu, ew_iu, sums_u, cnt_u, E);
    scatter_kernel<<<sgrd, sblk, 0, stream>>>(x_user, ei_ui, ew_ui, sums_i, cnt_i, E);
    finalize_kernel<<<fgrd_u, fblk, 0, stream>>>(sums_u, cnt_u, x_user, lnwu0, lnbu0, out_u, NU, 1);
    finalize_kernel<<<fgrd_i, fblk, 0, stream>>>(sums_i, cnt_i, x_item, lnwi0, lnbi0, out_i, NI, 1);

    // ---------------- layer 1 ----------------
    hipMemsetAsync(d_ws, 0, zero_bytes, stream);
    scatter_kernel<<<sgrd, sblk, 0, stream>>>(out_i, ei_iu, ew_iu, sums_u, cnt_u, E);
    scatter_kernel<<<sgrd, sblk, 0, stream>>>(out_u, ei_ui, ew_ui, sums_i, cnt_i, E);
    finalize_kernel<<<fgrd_u, fblk, 0, stream>>>(sums_u, cnt_u, out_u, lnwu1, lnbu1, out_u, NU, 0);
    finalize_kernel<<<fgrd_i, fblk, 0, stream>>>(sums_i, cnt_i, out_i, lnwi1, lnbi1, out_i, NI, 0);
}

// Round 2
// 1496.264 us; speedup vs baseline: 7.5302x; 7.5302x over previous
//
#include <hip/hip_runtime.h>

#define C 128
#define EPS 1e-5f

// ---------------- CSR build ----------------
__global__ __launch_bounds__(256) void count_kernel(
    const int* __restrict__ ei, int* __restrict__ cnt, int E)
{
    int e = blockIdx.x * blockDim.x + threadIdx.x;
    if (e < E) atomicAdd(&cnt[ei[E + e]], 1);
}

// single-block scan: counts -> exclusive prefix (row_ptr) + cursor copy
__global__ __launch_bounds__(1024) void scan_kernel(
    const int* __restrict__ cnt, int* __restrict__ rp, int* __restrict__ cur, int N)
{
    __shared__ int lds[1024];
    int t = threadIdx.x;
    int chunk = (N + 1023) / 1024;
    int s = t * chunk;
    int e = min(N, s + chunk);
    int local = 0;
    for (int i = s; i < e; ++i) local += cnt[i];
    lds[t] = local;
    __syncthreads();
    // Hillis-Steele inclusive scan over 1024 partials
    for (int off = 1; off < 1024; off <<= 1) {
        int v = 0;
        if (t >= off) v = lds[t - off];
        __syncthreads();
        if (t >= off) lds[t] += v;
        __syncthreads();
    }
    int prefix = (t == 0) ? 0 : lds[t - 1];
    for (int i = s; i < e; ++i) {
        rp[i] = prefix;
        cur[i] = prefix;
        prefix += cnt[i];
    }
    if (t == 1023) rp[N] = lds[1023];
}

__global__ __launch_bounds__(256) void fill_kernel(
    const int* __restrict__ ei, const float* __restrict__ ew,
    int* __restrict__ cur, int* __restrict__ csr_src, float* __restrict__ csr_w, int E)
{
    int e = blockIdx.x * blockDim.x + threadIdx.x;
    if (e < E) {
        int dst = ei[E + e];
        int pos = atomicAdd(&cur[dst], 1);
        csr_src[pos] = ei[e];
        csr_w[pos]  = ew[e];
    }
}

// ---------------- fused gather-aggregate + mean + residual + LN (+relu) ----------------
// one 64-lane wave per dst row; lane holds channels [2*lane, 2*lane+1] as float2.
__global__ __launch_bounds__(256) void sage_ln_kernel(
    const float* __restrict__ x_src,
    const float* __restrict__ x_dst,
    const int* __restrict__ rp,
    const int* __restrict__ csr_src,
    const float* __restrict__ csr_w,
    const float* __restrict__ lnw,
    const float* __restrict__ lnb,
    float* __restrict__ out,
    int N, int do_relu)
{
    int row  = blockIdx.x * 4 + (threadIdx.x >> 6);
    int lane = threadIdx.x & 63;
    if (row >= N) return;
    int start = rp[row];
    int end   = rp[row + 1];

    float2 acc = {0.0f, 0.0f};
    for (int base = start; base < end; base += 64) {
        int idx = base + lane;
        int src = 0;
        float w = 0.0f;
        if (idx < end) { src = csr_src[idx]; w = csr_w[idx]; }
        int n = min(64, end - base);
        for (int j = 0; j < n; ++j) {
            int   sj = __shfl(src, j, 64);
            float wj = __shfl(w,   j, 64);
            float2 v = ((const float2*)(x_src + (size_t)sj * C))[lane];
            acc.x += v.x * wj;
            acc.y += v.y * wj;
        }
    }

    float inv = 1.0f / fmaxf((float)(end - start), 1.0f);
    float2 xd = ((const float2*)(x_dst + (size_t)row * C))[lane];
    float2 v;
    v.x = acc.x * inv + xd.x;
    v.y = acc.y * inv + xd.y;

    float sum = v.x + v.y;
    float sq  = v.x * v.x + v.y * v.y;
    #pragma unroll
    for (int off = 32; off > 0; off >>= 1) {
        sum += __shfl_xor(sum, off, 64);
        sq  += __shfl_xor(sq,  off, 64);
    }
    float mu   = sum * (1.0f / C);
    float var  = sq * (1.0f / C) - mu * mu;
    float rstd = rsqrtf(var + EPS);

    float2 wv = ((const float2*)lnw)[lane];
    float2 bv = ((const float2*)lnb)[lane];
    float2 o;
    o.x = (v.x - mu) * rstd * wv.x + bv.x;
    o.y = (v.y - mu) * rstd * wv.y + bv.y;
    if (do_relu) { o.x = fmaxf(o.x, 0.0f); o.y = fmaxf(o.y, 0.0f); }
    ((float2*)(out + (size_t)row * C))[lane] = o;
}

extern "C" void kernel_launch(void* const* d_in, const int* in_sizes, int n_in,
                              void* d_out, int out_size, void* d_ws, size_t ws_size,
                              hipStream_t stream)
{
    const float* x_user = (const float*)d_in[0];
    const float* x_item = (const float*)d_in[1];
    const float* ew_ui  = (const float*)d_in[2];
    const float* ew_iu  = (const float*)d_in[3];
    const float* lnwu0  = (const float*)d_in[4];
    const float* lnbu0  = (const float*)d_in[5];
    const float* lnwu1  = (const float*)d_in[6];
    const float* lnbu1  = (const float*)d_in[7];
    const float* lnwi0  = (const float*)d_in[8];
    const float* lnbi0  = (const float*)d_in[9];
    const float* lnwi1  = (const float*)d_in[10];
    const float* lnbi1  = (const float*)d_in[11];
    const int*   ei_ui  = (const int*)d_in[12];  // src=user, dst=item
    const int*   ei_iu  = (const int*)d_in[13];  // src=item, dst=user

    const int NU = in_sizes[0] / C;
    const int NI = in_sizes[1] / C;
    const int E  = in_sizes[2];

    float* out   = (float*)d_out;
    float* out_u = out;
    float* out_i = out + (size_t)NU * C;

    // ---- ws layout ----
    char* p = (char*)d_ws;
    float* act_u    = (float*)p;              p += (size_t)NU * C * sizeof(float);
    int*   csr_src_u = (int*)p;               p += (size_t)E * sizeof(int);
    float* csr_w_u   = (float*)p;             p += (size_t)E * sizeof(float);
    int*   csr_src_i = (int*)p;               p += (size_t)E * sizeof(int);
    float* csr_w_i   = (float*)p;             p += (size_t)E * sizeof(float);
    int*   cnt_u     = (int*)p;               p += (size_t)NU * sizeof(int);
    int*   cnt_i     = (int*)p;               p += (size_t)NI * sizeof(int);
    int*   rp_u      = (int*)p;               p += (size_t)(NU + 1) * sizeof(int);
    int*   rp_i      = (int*)p;               p += (size_t)(NI + 1) * sizeof(int);
    int*   cur_u     = (int*)p;               p += (size_t)NU * sizeof(int);
    int*   cur_i     = (int*)p;               p += (size_t)NI * sizeof(int);

    dim3 eblk(256), egrd((E + 255) / 256);
    dim3 fblk(256);
    dim3 fgrd_u((NU + 3) / 4), fgrd_i((NI + 3) / 4);

    // ---- build CSR (by destination) for both edge types ----
    hipMemsetAsync(cnt_u, 0, (size_t)(NU + NI) * sizeof(int), stream); // cnt_u+cnt_i contiguous
    count_kernel<<<egrd, eblk, 0, stream>>>(ei_iu, cnt_u, E);
    count_kernel<<<egrd, eblk, 0, stream>>>(ei_ui, cnt_i, E);
    scan_kernel<<<1, 1024, 0, stream>>>(cnt_u, rp_u, cur_u, NU);
    scan_kernel<<<1, 1024, 0, stream>>>(cnt_i, rp_i, cur_i, NI);
    fill_kernel<<<egrd, eblk, 0, stream>>>(ei_iu, ew_iu, cur_u, csr_src_u, csr_w_u, E);
    fill_kernel<<<egrd, eblk, 0, stream>>>(ei_ui, ew_ui, cur_i, csr_src_i, csr_w_i, E);

    // ---- layer 0 ----
    sage_ln_kernel<<<fgrd_u, fblk, 0, stream>>>(x_item, x_user, rp_u, csr_src_u, csr_w_u,
                                                lnwu0, lnbu0, act_u, NU, 1);
    sage_ln_kernel<<<fgrd_i, fblk, 0, stream>>>(x_user, x_item, rp_i, csr_src_i, csr_w_i,
                                                lnwi0, lnbi0, out_i, NI, 1);

    // ---- layer 1 (user kernel MUST precede item kernel: it gathers from out_i) ----
    sage_ln_kernel<<<fgrd_u, fblk, 0, stream>>>(out_i, act_u, rp_u, csr_src_u, csr_w_u,
                                                lnwu1, lnbu1, out_u, NU, 0);
    sage_ln_kernel<<<fgrd_i, fblk, 0, stream>>>(act_u, out_i, rp_i, csr_src_i, csr_w_i,
                                                lnwi1, lnbi1, out_i, NI, 0);
}

// Round 3
// 999.017 us; speedup vs baseline: 11.2783x; 1.4977x over previous
//
#include <hip/hip_runtime.h>

#define C 128
#define EPS 1e-5f
#define SCAN_TILE 4096   // 1024 threads x 4 elements

// ---------------- combined degree count over both edge types ----------------
// bucket: dst in [0,NU) for iu edges, NU + dst for ui edges.
__global__ __launch_bounds__(256) void count_kernel(
    const int* __restrict__ ei_iu, const int* __restrict__ ei_ui,
    int* __restrict__ cnt, int E, int NU)
{
    int t = blockIdx.x * blockDim.x + threadIdx.x;
    if (t < E)            atomicAdd(&cnt[ei_iu[E + t]], 1);
    else if (t < 2 * E)   atomicAdd(&cnt[NU + ei_ui[E + (t - E)]], 1);
}

// ---------------- 3-phase multiblock exclusive scan ----------------
__global__ __launch_bounds__(1024) void scan_partials(
    const int* __restrict__ cnt, int* __restrict__ partials, int NTOT)
{
    int base = blockIdx.x * SCAN_TILE + threadIdx.x * 4;
    int s = 0;
    #pragma unroll
    for (int k = 0; k < 4; ++k)
        if (base + k < NTOT) s += cnt[base + k];
    #pragma unroll
    for (int off = 32; off > 0; off >>= 1) s += __shfl_xor(s, off, 64);
    __shared__ int ws[16];
    int wave = threadIdx.x >> 6;
    if ((threadIdx.x & 63) == 0) ws[wave] = s;
    __syncthreads();
    if (threadIdx.x == 0) {
        int tot = 0;
        for (int i = 0; i < 16; ++i) tot += ws[i];
        partials[blockIdx.x] = tot;
    }
}

__global__ __launch_bounds__(1024) void scan_spine(
    int* __restrict__ partials, int* __restrict__ rp, int NPART, int NTOT)
{
    __shared__ int lds[1024];
    int t = threadIdx.x;
    lds[t] = (t < NPART) ? partials[t] : 0;
    __syncthreads();
    for (int off = 1; off < 1024; off <<= 1) {
        int v = (t >= off) ? lds[t - off] : 0;
        __syncthreads();
        lds[t] += v;
        __syncthreads();
    }
    if (t < NPART) partials[t] = (t == 0) ? 0 : lds[t - 1];
    if (t == 0) rp[NTOT] = lds[1023];   // grand total (zero-padded scan)
}

__global__ __launch_bounds__(1024) void scan_write(
    const int* __restrict__ cnt, const int* __restrict__ partials,
    int* __restrict__ rp, int* __restrict__ cur, int NTOT)
{
    __shared__ int lds[1024];
    int t = threadIdx.x;
    int base = blockIdx.x * SCAN_TILE + t * 4;
    int v0 = 0, v1 = 0, v2 = 0, v3 = 0;
    if (base + 0 < NTOT) v0 = cnt[base + 0];
    if (base + 1 < NTOT) v1 = cnt[base + 1];
    if (base + 2 < NTOT) v2 = cnt[base + 2];
    if (base + 3 < NTOT) v3 = cnt[base + 3];
    lds[t] = v0 + v1 + v2 + v3;
    __syncthreads();
    for (int off = 1; off < 1024; off <<= 1) {
        int v = (t >= off) ? lds[t - off] : 0;
        __syncthreads();
        lds[t] += v;
        __syncthreads();
    }
    int p = partials[blockIdx.x] + ((t == 0) ? 0 : lds[t - 1]);
    if (base + 0 < NTOT) { rp[base + 0] = p; cur[base + 0] = p; p += v0; }
    if (base + 1 < NTOT) { rp[base + 1] = p; cur[base + 1] = p; p += v1; }
    if (base + 2 < NTOT) { rp[base + 2] = p; cur[base + 2] = p; p += v2; }
    if (base + 3 < NTOT) { rp[base + 3] = p; cur[base + 3] = p; }
}

// ---------------- combined CSR fill ----------------
__global__ __launch_bounds__(256) void fill_kernel(
    const int* __restrict__ ei_iu, const float* __restrict__ ew_iu,
    const int* __restrict__ ei_ui, const float* __restrict__ ew_ui,
    int* __restrict__ cur, int* __restrict__ csr_src, float* __restrict__ csr_w,
    int E, int NU)
{
    int t = blockIdx.x * blockDim.x + threadIdx.x;
    if (t < E) {
        int pos = atomicAdd(&cur[ei_iu[E + t]], 1);
        csr_src[pos] = ei_iu[t];
        csr_w[pos]  = ew_iu[t];
    } else if (t < 2 * E) {
        int e = t - E;
        int pos = atomicAdd(&cur[NU + ei_ui[E + e]], 1);
        csr_src[pos] = ei_ui[e];
        csr_w[pos]  = ew_ui[e];
    }
}

// ---------------- fused gather-aggregate + mean + residual + LN (+relu) ----------------
// one 64-lane wave per dst row; 2 edges processed per iteration;
// lane = 32*sub + ch_lane; lane holds channels [4*ch_lane .. 4*ch_lane+3] of edge `sub`.
__global__ __launch_bounds__(256) void sage_ln_kernel(
    const float* __restrict__ x_src,
    const float* __restrict__ x_dst,
    const int* __restrict__ rp,
    const int* __restrict__ csr_src,
    const float* __restrict__ csr_w,
    const float* __restrict__ lnw,
    const float* __restrict__ lnb,
    float* __restrict__ out,
    int N, int do_relu)
{
    int row  = blockIdx.x * 4 + (threadIdx.x >> 6);
    int lane = threadIdx.x & 63;
    int sub  = lane >> 5;       // which of the 2 edges this half-wave handles
    int cl   = lane & 31;       // channel-group lane (float4 => 4 channels)
    if (row >= N) return;
    int start = rp[row];
    int end   = rp[row + 1];

    float4 acc = {0.f, 0.f, 0.f, 0.f};
    for (int base = start; base < end; base += 64) {
        int idx = base + lane;
        int src = 0;
        float w = 0.0f;
        if (idx < end) { src = csr_src[idx]; w = csr_w[idx]; }
        int n = min(64, end - base);
        for (int j = 0; 2 * j < n; ++j) {
            int   sj = __shfl(src, 2 * j + sub, 64);
            float wj = __shfl(w,   2 * j + sub, 64);
            float4 v = ((const float4*)(x_src + (size_t)sj * C))[cl];
            acc.x += v.x * wj;
            acc.y += v.y * wj;
            acc.z += v.z * wj;
            acc.w += v.w * wj;
        }
    }
    // combine the two half-wave partial sums (both halves end with full sum)
    acc.x += __shfl_xor(acc.x, 32, 64);
    acc.y += __shfl_xor(acc.y, 32, 64);
    acc.z += __shfl_xor(acc.z, 32, 64);
    acc.w += __shfl_xor(acc.w, 32, 64);

    float inv = 1.0f / fmaxf((float)(end - start), 1.0f);
    float4 xd = ((const float4*)(x_dst + (size_t)row * C))[cl];
    float4 v;
    v.x = acc.x * inv + xd.x;
    v.y = acc.y * inv + xd.y;
    v.z = acc.z * inv + xd.z;
    v.w = acc.w * inv + xd.w;

    float sum = v.x + v.y + v.z + v.w;
    float sq  = v.x * v.x + v.y * v.y + v.z * v.z + v.w * v.w;
    #pragma unroll
    for (int off = 16; off > 0; off >>= 1) {
        sum += __shfl_xor(sum, off, 64);
        sq  += __shfl_xor(sq,  off, 64);
    }
    float mu   = sum * (1.0f / C);
    float var  = sq * (1.0f / C) - mu * mu;
    float rstd = rsqrtf(var + EPS);

    float4 wv = ((const float4*)lnw)[cl];
    float4 bv = ((const float4*)lnb)[cl];
    float4 o;
    o.x = (v.x - mu) * rstd * wv.x + bv.x;
    o.y = (v.y - mu) * rstd * wv.y + bv.y;
    o.z = (v.z - mu) * rstd * wv.z + bv.z;
    o.w = (v.w - mu) * rstd * wv.w + bv.w;
    if (do_relu) {
        o.x = fmaxf(o.x, 0.f); o.y = fmaxf(o.y, 0.f);
        o.z = fmaxf(o.z, 0.f); o.w = fmaxf(o.w, 0.f);
    }
    if (sub == 0) ((float4*)(out + (size_t)row * C))[cl] = o;
}

extern "C" void kernel_launch(void* const* d_in, const int* in_sizes, int n_in,
                              void* d_out, int out_size, void* d_ws, size_t ws_size,
                              hipStream_t stream)
{
    const float* x_user = (const float*)d_in[0];
    const float* x_item = (const float*)d_in[1];
    const float* ew_ui  = (const float*)d_in[2];
    const float* ew_iu  = (const float*)d_in[3];
    const float* lnwu0  = (const float*)d_in[4];
    const float* lnbu0  = (const float*)d_in[5];
    const float* lnwu1  = (const float*)d_in[6];
    const float* lnbu1  = (const float*)d_in[7];
    const float* lnwi0  = (const float*)d_in[8];
    const float* lnbi0  = (const float*)d_in[9];
    const float* lnwi1  = (const float*)d_in[10];
    const float* lnbi1  = (const float*)d_in[11];
    const int*   ei_ui  = (const int*)d_in[12];  // src=user, dst=item
    const int*   ei_iu  = (const int*)d_in[13];  // src=item, dst=user

    const int NU = in_sizes[0] / C;
    const int NI = in_sizes[1] / C;
    const int E  = in_sizes[2];
    const int NTOT = NU + NI;

    float* out   = (float*)d_out;
    float* out_u = out;
    float* out_i = out + (size_t)NU * C;

    // ---- ws layout ----
    char* p = (char*)d_ws;
    float* act_u   = (float*)p;    p += (size_t)NU * C * sizeof(float);
    int*   csr_src = (int*)p;      p += (size_t)2 * E * sizeof(int);
    float* csr_w   = (float*)p;    p += (size_t)2 * E * sizeof(float);
    int*   cnt     = (int*)p;      p += (size_t)NTOT * sizeof(int);
    int*   rp      = (int*)p;      p += (size_t)(NTOT + 1) * sizeof(int);
    int*   cur     = (int*)p;      p += (size_t)NTOT * sizeof(int);
    int*   partials = (int*)p;     p += (size_t)1024 * sizeof(int);

    const int NPART = (NTOT + SCAN_TILE - 1) / SCAN_TILE;

    dim3 eblk(256), egrd((2 * E + 255) / 256);
    dim3 fblk(256);
    dim3 fgrd_u((NU + 3) / 4), fgrd_i((NI + 3) / 4);

    // ---- build combined CSR (by destination bucket) ----
    hipMemsetAsync(cnt, 0, (size_t)NTOT * sizeof(int), stream);
    count_kernel<<<egrd, eblk, 0, stream>>>(ei_iu, ei_ui, cnt, E, NU);
    scan_partials<<<NPART, 1024, 0, stream>>>(cnt, partials, NTOT);
    scan_spine<<<1, 1024, 0, stream>>>(partials, rp, NPART, NTOT);
    scan_write<<<NPART, 1024, 0, stream>>>(cnt, partials, rp, cur, NTOT);
    fill_kernel<<<egrd, eblk, 0, stream>>>(ei_iu, ew_iu, ei_ui, ew_ui,
                                           cur, csr_src, csr_w, E, NU);

    // ---- layer 0 ----
    sage_ln_kernel<<<fgrd_u, fblk, 0, stream>>>(x_item, x_user, rp, csr_src, csr_w,
                                                lnwu0, lnbu0, act_u, NU, 1);
    sage_ln_kernel<<<fgrd_i, fblk, 0, stream>>>(x_user, x_item, rp + NU, csr_src, csr_w,
                                                lnwi0, lnbi0, out_i, NI, 1);

    // ---- layer 1 (user kernel MUST precede item kernel: it gathers from out_i) ----
    sage_ln_kernel<<<fgrd_u, fblk, 0, stream>>>(out_i, act_u, rp, csr_src, csr_w,
                                                lnwu1, lnbu1, out_u, NU, 0);
    sage_ln_kernel<<<fgrd_i, fblk, 0, stream>>>(act_u, out_i, rp + NU, csr_src, csr_w,
                                                lnwi1, lnbi1, out_i, NI, 0);
}